// Round 6
// baseline (3535.096 us; speedup 1.0000x reference)
//
#include <hip/hip_runtime.h>

typedef unsigned short u16;
typedef unsigned int u32;
typedef __attribute__((ext_vector_type(8))) short bf16x8;
typedef __attribute__((ext_vector_type(8))) u16 u16x8;
typedef __attribute__((ext_vector_type(4))) u16 u16x4;
typedef __attribute__((ext_vector_type(4))) u32 u32x4;
typedef __attribute__((ext_vector_type(4))) float f32x4;

#define DEV static __device__ __forceinline__

DEV u16 f2bf(float f) {
    union { float f; u32 u; } v; v.f = f;
    u32 r = v.u + 0x7FFFu + ((v.u >> 16) & 1u);
    return (u16)(r >> 16);
}

DEV u32 cvtpk(float lo, float hi) {
    u32 r;
    asm("v_cvt_pk_bf16_f32 %0, %1, %2" : "=v"(r) : "v"(lo), "v"(hi));
    return r;
}

DEV int swzc(int r, int c) { return c ^ ((r >> 1) & 3); }

DEV void gload_lds16(const void* g, void* l) {
    __builtin_amdgcn_global_load_lds((const __attribute__((address_space(1))) void*)g,
                                     (__attribute__((address_space(3))) void*)l, 16, 0, 0);
}

// ---------------------------------------------------------------------------
// Hybrid big-pass GEMM: C_part[s][M][BN] = A[M][K] @ Bt[BN-panel][K]^T.
// A (the HBM stream): nt-load -> regs -> LDS (triple-buffered 4KB tiles).
// B (L2-hot panel): direct global->VGPR fragments, double-buffered regs.
// Manual lgkmcnt(0)+s_barrier per step (NO vmcnt drain): issue order makes
// all waits counted -> A prefetch rides >=1 full step, B rides 1 step.
// Wave tile 64x64 (FI=FJ=4). WAVES in {2,4}. AF32: A fp32 -> cvt_pk.
// DUMPA: stage also nt-stores the bf16 A tile to Adump (exact cover, no dup).
// ---------------------------------------------------------------------------
template<int WAVES, int MINW, bool AF32, bool DUMPA>
__global__ __launch_bounds__(WAVES * 64, MINW) void pgemm_k(
    const void* __restrict__ Ap, const u16* __restrict__ Bt,
    float* __restrict__ Cp, u16* __restrict__ Adump,
    int M, int K, int lda, int ldb, int nRT, int KCH, int cpx)
{
    constexpr int NT = WAVES * 64;
    constexpr int BN = WAVES * 64;
    constexpr int CPT = 256 / NT;           // 16B-chunks (8 elems) per thread of the 64x32 tile
    __shared__ u16 ldsA[3][64 * 32];

    const int tid = threadIdx.x;
    int bid0 = blockIdx.x;
    int bid = (bid0 % 8) * cpx + bid0 / 8;  // XCD-contiguous (grid % 8 == 0)
    const int rt = bid % nRT;
    const int s  = bid / nRT;
    const int m0 = rt * 64;
    const int kBeg = s * KCH;
    const int kEnd = (K < kBeg + KCH) ? K : (kBeg + KCH);
    const int nsteps = (kEnd - kBeg) >> 5;
    const int kLast = kBeg + (nsteps - 1) * 32;

    const int wv = tid >> 6, l = tid & 63;
    const int wn = wv * 64;
    const int lr = l & 15, lg = l >> 4;

    // staging map: slot -> (row r, 16B chunk q)
    int soff[CPT], slds[CPT];
    bool svalid[CPT];
    #pragma unroll
    for (int u = 0; u < CPT; u++) {
        int slot = u * NT + tid;
        int r = slot >> 2, q = slot & 3;
        int rr = m0 + r;
        svalid[u] = rr < M;
        int gm = svalid[u] ? rr : (M - 1);
        soff[u] = gm * lda + q * 8;         // element offset (fits int)
        slds[u] = r * 32 + swzc(r, q) * 8;
    }
    int boff[4];
    #pragma unroll
    for (int j = 0; j < 4; j++) boff[j] = (wn + j * 16 + lr) * ldb + lg * 8;

    f32x4 acc[4][4] = {};
    const u16* Ab = (const u16*)Ap;
    const float* Af = (const float*)Ap;

    f32x4 Rf[CPT][2];
    bf16x8 Rh[CPT];
    bf16x8 Ba[4], Bb[4];

    auto issueA = [&](int kc) {
        if constexpr (AF32) {
            #pragma unroll
            for (int u = 0; u < CPT; u++) {
                const f32x4* p = (const f32x4*)(Af + (size_t)(soff[u] + kc));
                Rf[u][0] = __builtin_nontemporal_load(p);
                Rf[u][1] = __builtin_nontemporal_load(p + 1);
            }
        } else {
            #pragma unroll
            for (int u = 0; u < CPT; u++)
                Rh[u] = __builtin_nontemporal_load((const bf16x8*)(Ab + (size_t)(soff[u] + kc)));
        }
    };
    auto commitA = [&](int buf, int kc) {
        #pragma unroll
        for (int u = 0; u < CPT; u++) {
            if constexpr (AF32) {
                u32x4 pk;
                pk[0] = cvtpk(Rf[u][0][0], Rf[u][0][1]);
                pk[1] = cvtpk(Rf[u][0][2], Rf[u][0][3]);
                pk[2] = cvtpk(Rf[u][1][0], Rf[u][1][1]);
                pk[3] = cvtpk(Rf[u][1][2], Rf[u][1][3]);
                *(u32x4*)&ldsA[buf][slds[u]] = pk;
                if constexpr (DUMPA) {
                    if (svalid[u])
                        __builtin_nontemporal_store(pk, (u32x4*)(Adump + (size_t)(soff[u] + kc)));
                }
            } else {
                *(bf16x8*)&ldsA[buf][slds[u]] = Rh[u];
            }
        }
    };
    auto issueB = [&](bf16x8 (&B)[4], int kc) {
        #pragma unroll
        for (int j = 0; j < 4; j++)
            B[j] = *(const bf16x8*)(Bt + (size_t)(boff[j] + kc));
    };
    auto mfma16 = [&](bf16x8 (&B)[4], int buf) {
        bf16x8 af[4];
        #pragma unroll
        for (int i = 0; i < 4; i++) {
            int r = i * 16 + lr;
            af[i] = *(const bf16x8*)&ldsA[buf][r * 32 + swzc(r, lg) * 8];
        }
        #pragma unroll
        for (int i = 0; i < 4; i++)
            #pragma unroll
            for (int j = 0; j < 4; j++)
                acc[i][j] = __builtin_amdgcn_mfma_f32_16x16x32_bf16(af[i], B[j], acc[i][j], 0, 0, 0);
    };

    // prologue: A(k0)+B(k0) in flight; buf0 committed; A(k1) in flight
    issueA(kBeg);
    issueB(Ba, kBeg);
    commitA(0, kBeg);                                   // waits A(k0) only (counted)
    issueA(nsteps > 1 ? kBeg + 32 : kBeg);
    asm volatile("s_waitcnt lgkmcnt(0)" ::: "memory");
    __builtin_amdgcn_s_barrier();
    __builtin_amdgcn_sched_barrier(0);

    for (int t = 0; t < nsteps; t++) {
        const int kc = kBeg + t * 32;
        int kn1 = kc + 32; if (kn1 > kLast) kn1 = kLast;
        int kn2 = kc + 64; if (kn2 > kLast) kn2 = kLast;
        const int bufc = t % 3, bufn = (t + 1) % 3;
        const bool hasNext = (t + 1 < nsteps);
        if ((t & 1) == 0) {
            issueB(Bb, kn1);                            // newest -> rides through waits
            mfma16(Ba, bufc);                           // waits vmcnt: B_cur + older A retired
            if (hasNext) commitA(bufn, kn1);            // waits vmcnt: A_next retired
            issueA(kn2);
        } else {
            issueB(Ba, kn1);
            mfma16(Bb, bufc);
            if (hasNext) commitA(bufn, kn1);
            issueA(kn2);
        }
        asm volatile("s_waitcnt lgkmcnt(0)" ::: "memory");
        __builtin_amdgcn_s_barrier();                   // NO vmcnt drain: prefetches stay in flight
        __builtin_amdgcn_sched_barrier(0);
    }

    float* Cbase = Cp + (size_t)s * M * BN;
    #pragma unroll
    for (int i = 0; i < 4; i++)
        #pragma unroll
        for (int j = 0; j < 4; j++)
            #pragma unroll
            for (int e = 0; e < 4; e++) {
                int row = m0 + i * 16 + lg * 4 + e;
                int col = wn + j * 16 + lr;
                if (row < M)
                    __builtin_nontemporal_store(acc[i][j][e], &Cbase[(size_t)row * BN + col]);
            }
}

// ---------------------------------------------------------------------------
// Small-GEMM kernel (S1..S5): LDS-staged, unchanged from round 3.
// ---------------------------------------------------------------------------
template<int BN, int MINW, bool AF32, bool BF32, int BIAS, bool RELU, bool OUTBF>
__global__ __launch_bounds__(256, MINW) void gemm_k(
    const void* __restrict__ Ap, const void* __restrict__ Bp, void* __restrict__ Cp,
    const float* __restrict__ bias,
    int M, int N, int K, int lda, int ldb, int nRT, int nNT, int KCH)
{
    constexpr int BM = 64;
    constexpr int WN = BN / 4;
    constexpr int FI = 4;
    constexpr int FJ = WN / 16;
    constexpr int CPT = BN / 64;
    __shared__ u16 ldsA[2][BM * 32];
    __shared__ u16 ldsB[2][BN * 32];

    const int tid = threadIdx.x;
    int bid = blockIdx.x;
    const int rt = bid % nRT; bid /= nRT;
    const int nt = bid % nNT;
    const int s  = bid / nNT;
    const int m0 = rt * BM, n0 = nt * BN;
    const int kBeg = s * KCH;
    const int kEnd = (K < kBeg + KCH) ? K : (kBeg + KCH);
    const int nsteps = (kEnd - kBeg) >> 5;

    const int w = tid >> 6, l = tid & 63;
    const int wn = w * WN;
    const int lr = l & 15, lg = l >> 4;

    f32x4 acc[FI][FJ] = {};
    float aR[8], bR[8];

    auto aIssue = [&](int buf, int k0) {
        if constexpr (AF32) {
            const float* A = (const float*)Ap;
            int r = tid >> 2, q = tid & 3;
            int gm = m0 + r; gm = (gm < M) ? gm : (M - 1);
            const float4* src = (const float4*)(A + (size_t)gm * lda + k0 + q * 8);
            float4 v0 = src[0], v1 = src[1];
            aR[0]=v0.x; aR[1]=v0.y; aR[2]=v0.z; aR[3]=v0.w;
            aR[4]=v1.x; aR[5]=v1.y; aR[6]=v1.z; aR[7]=v1.w;
        } else {
            const u16* A = (const u16*)Ap;
            int r = tid >> 2, cs = tid & 3;
            int c = swzc(r, cs);
            int gm = m0 + r; gm = (gm < M) ? gm : (M - 1);
            gload_lds16(A + (size_t)gm * lda + k0 + c * 8, &ldsA[buf][tid * 8]);
        }
    };
    auto aCommit = [&](int buf) {
        if constexpr (AF32) {
            int r = tid >> 2, q = tid & 3;
            u16x8 pk;
            #pragma unroll
            for (int e = 0; e < 8; e++) pk[e] = f2bf(aR[e]);
            *(u16x8*)&ldsA[buf][r * 32 + swzc(r, q) * 8] = pk;
        }
    };
    auto bIssue = [&](int buf, int k0) {
        if constexpr (BF32) {
            const float* B = (const float*)Bp;
            int r = tid >> 2, q = tid & 3;
            int gn = n0 + r; gn = (gn < N) ? gn : (N - 1);
            const float4* src = (const float4*)(B + (size_t)gn * ldb + k0 + q * 8);
            float4 v0 = src[0], v1 = src[1];
            bR[0]=v0.x; bR[1]=v0.y; bR[2]=v0.z; bR[3]=v0.w;
            bR[4]=v1.x; bR[5]=v1.y; bR[6]=v1.z; bR[7]=v1.w;
        } else {
            const u16* B = (const u16*)Bp;
            #pragma unroll
            for (int u = 0; u < CPT; u++) {
                int slot = u * 256 + tid;
                int r = slot >> 2, cs = slot & 3;
                int c = swzc(r, cs);
                int gn = n0 + r; gn = (gn < N) ? gn : (N - 1);
                gload_lds16(B + (size_t)gn * ldb + k0 + c * 8, &ldsB[buf][slot * 8]);
            }
        }
    };
    auto bCommit = [&](int buf) {
        if constexpr (BF32) {
            int r = tid >> 2, q = tid & 3;
            u16x8 pk;
            #pragma unroll
            for (int e = 0; e < 8; e++) pk[e] = f2bf(bR[e]);
            *(u16x8*)&ldsB[buf][r * 32 + swzc(r, q) * 8] = pk;
        }
    };

    aIssue(0, kBeg); bIssue(0, kBeg);
    aCommit(0); bCommit(0);
    __syncthreads();

    for (int t = 0; t < nsteps; t++) {
        const int k = kBeg + t * 32;
        const int cur = t & 1, nxt = cur ^ 1;
        if (t + 1 < nsteps) { aIssue(nxt, k + 32); bIssue(nxt, k + 32); }

        bf16x8 af[FI], bfr[FJ];
        #pragma unroll
        for (int i = 0; i < FI; i++) {
            int r = i * 16 + lr;
            af[i] = *(const bf16x8*)&ldsA[cur][r * 32 + swzc(r, lg) * 8];
        }
        #pragma unroll
        for (int j = 0; j < FJ; j++) {
            int r = wn + j * 16 + lr;
            bfr[j] = *(const bf16x8*)&ldsB[cur][r * 32 + swzc(r, lg) * 8];
        }
        #pragma unroll
        for (int i = 0; i < FI; i++)
            #pragma unroll
            for (int j = 0; j < FJ; j++)
                acc[i][j] = __builtin_amdgcn_mfma_f32_16x16x32_bf16(af[i], bfr[j], acc[i][j], 0, 0, 0);

        if (t + 1 < nsteps) { aCommit(nxt); bCommit(nxt); }
        __syncthreads();
    }

    #pragma unroll
    for (int i = 0; i < FI; i++)
        #pragma unroll
        for (int j = 0; j < FJ; j++)
            #pragma unroll
            for (int e = 0; e < 4; e++) {
                int row = m0 + i * 16 + lg * 4 + e;
                int col = n0 + wn + j * 16 + lr;
                if (row < M && col < N) {
                    float v = acc[i][j][e];
                    if constexpr (BIAS == 1) v += bias[row];
                    if constexpr (BIAS == 2) v += bias[col];
                    if constexpr (RELU) v = fmaxf(v, 0.0f);
                    if constexpr (OUTBF) ((u16*)Cp)[(size_t)row * N + col] = f2bf(v);
                    else ((float*)Cp)[(size_t)s * M * N + (size_t)row * N + col] = v;
                }
            }
}

// fused: sum split-K partials + residual -> LayerNorm -> relu -> bf16 (+f32) out. D=256.
__global__ __launch_bounds__(256) void ln_k(
    const float* __restrict__ part, long pStride, int nPart,
    const float* __restrict__ resid, const float* __restrict__ gamma, const float* __restrict__ beta,
    u16* __restrict__ obf, float* __restrict__ of32, int M)
{
    const int w = threadIdx.x >> 6, l = threadIdx.x & 63;
    for (int row = blockIdx.x * 4 + w; row < M; row += gridDim.x * 4) {
        size_t base = (size_t)row * 256 + l * 4;
        float4 v = *(const float4*)(part + base);
        for (int s = 1; s < nPart; s++) {
            float4 u = *(const float4*)(part + (size_t)s * pStride + base);
            v.x += u.x; v.y += u.y; v.z += u.z; v.w += u.w;
        }
        float4 r = *(const float4*)(resid + base);
        v.x += r.x; v.y += r.y; v.z += r.z; v.w += r.w;
        float sum = v.x + v.y + v.z + v.w;
        float sq  = v.x*v.x + v.y*v.y + v.z*v.z + v.w*v.w;
        #pragma unroll
        for (int o = 32; o >= 1; o >>= 1) {
            sum += __shfl_xor(sum, o, 64);
            sq  += __shfl_xor(sq, o, 64);
        }
        float mu  = sum * (1.0f / 256.0f);
        float var = sq * (1.0f / 256.0f) - mu * mu;
        float sc  = rsqrtf(var + 1e-5f);
        int c = l * 4;
        float y0 = fmaxf((v.x - mu) * sc * gamma[c + 0] + beta[c + 0], 0.0f);
        float y1 = fmaxf((v.y - mu) * sc * gamma[c + 1] + beta[c + 1], 0.0f);
        float y2 = fmaxf((v.z - mu) * sc * gamma[c + 2] + beta[c + 2], 0.0f);
        float y3 = fmaxf((v.w - mu) * sc * gamma[c + 3] + beta[c + 3], 0.0f);
        u16x4 pk; pk[0] = f2bf(y0); pk[1] = f2bf(y1); pk[2] = f2bf(y2); pk[3] = f2bf(y3);
        *(u16x4*)(obf + base) = pk;
        if (of32) { float4 o4; o4.x = y0; o4.y = y1; o4.z = y2; o4.w = y3; *(float4*)(of32 + base) = o4; }
    }
}

// sum split-K partials -> f32 out + bf16 copy (embedding)
__global__ __launch_bounds__(256) void sum_k(
    const float* __restrict__ p, long pStride, int nPart,
    float* __restrict__ of, u16* __restrict__ ob, int total4)
{
    int i = blockIdx.x * 256 + threadIdx.x;
    if (i >= total4) return;
    size_t b = (size_t)i * 4;
    float4 v = *(const float4*)(p + b);
    for (int s = 1; s < nPart; s++) {
        float4 u = *(const float4*)(p + (size_t)s * pStride + b);
        v.x += u.x; v.y += u.y; v.z += u.z; v.w += u.w;
    }
    *(float4*)(of + b) = v;
    u16x4 pk; pk[0] = f2bf(v.x); pk[1] = f2bf(v.y); pk[2] = f2bf(v.z); pk[3] = f2bf(v.w);
    *(u16x4*)(ob + b) = pk;
}

// transpose + bf16-convert the 5 weight matrices.
__global__ __launch_bounds__(256) void prep_k(
    const float* __restrict__ s0, const float* __restrict__ s1, const float* __restrict__ s2,
    const float* __restrict__ s3, const float* __restrict__ s4,
    u16* __restrict__ d0, u16* __restrict__ d1, u16* __restrict__ d2,
    u16* __restrict__ d3, u16* __restrict__ d4)
{
    int i = blockIdx.x * 256 + threadIdx.x;
    if (i < 65536) {
        int o = i >> 8, ii = i & 255; d0[i] = f2bf(s0[(size_t)ii * 256 + o]);
    } else if (i < 131072) {
        int j = i - 65536; int o = j >> 8, ii = j & 255; d1[j] = f2bf(s1[(size_t)ii * 256 + o]);
    } else if (i < 163840) {
        int j = i - 131072; int o = j >> 8, ii = j & 255; d2[j] = f2bf(s2[(size_t)ii * 128 + o]);
    } else if (i < 180224) {
        int j = i - 163840; int o = j >> 7, ii = j & 127; d3[j] = f2bf(s3[(size_t)ii * 128 + o]);
    } else if (i < 196608) {
        int j = i - 180224; int o = j >> 7, ii = j & 127; d4[j] = f2bf(s4[(size_t)ii * 128 + o]);
    }
}

extern "C" void kernel_launch(void* const* d_in, const int* in_sizes, int n_in,
                              void* d_out, int out_size, void* d_ws, size_t ws_size,
                              hipStream_t stream)
{
    if (n_in < 16) return;
    const int NN = 12000, DD = 256, EE = 128;
    const float* x   = (const float*)d_in[0];
    const float* adj = (const float*)d_in[1];
    const float* W1  = (const float*)d_in[2];
    const float* b1  = (const float*)d_in[3];
    const float* g1  = (const float*)d_in[4];
    const float* be1 = (const float*)d_in[5];
    const float* W2  = (const float*)d_in[6];
    const float* b2  = (const float*)d_in[7];
    const float* g2  = (const float*)d_in[8];
    const float* be2 = (const float*)d_in[9];
    const float* W3  = (const float*)d_in[10];
    const float* b3  = (const float*)d_in[11];
    const float* Wp1 = (const float*)d_in[12];
    const float* bp1 = (const float*)d_in[13];
    const float* Wp2 = (const float*)d_in[14];
    const float* bp2 = (const float*)d_in[15];
    float* zOut   = (float*)d_out;
    float* embOut = zOut + (size_t)NN * EE;

    char* ws = (char*)d_ws;
    size_t off = 0;
    auto alloc = [&](size_t bytes) -> void* {
        off = (off + 255) & ~(size_t)255;
        void* p = ws + off; off += bytes; return p;
    };

    const size_t adjElems = (size_t)NN * NN;
    bool cacheAdj = ws_size >= adjElems * 2 + 100000000ULL;
    u16* adjb = cacheAdj ? (u16*)alloc(adjElems * 2) : nullptr;

    u16* xW1t   = (u16*)alloc((size_t)DD * NN * 2);
    u16* hW2t   = (u16*)alloc((size_t)DD * NN * 2);
    u16* h2W3t  = (u16*)alloc((size_t)EE * NN * 2);
    u16* hbf    = (u16*)alloc((size_t)NN * DD * 2);
    float* hf32 = (float*)alloc((size_t)NN * DD * 4);
    u16* h2bf   = (u16*)alloc((size_t)NN * DD * 2);
    u16* embbf  = (u16*)alloc((size_t)NN * EE * 2);
    u16* p1bf   = (u16*)alloc((size_t)NN * EE * 2);
    u16* W1t    = (u16*)alloc(65536 * 2);
    u16* W2t    = (u16*)alloc(65536 * 2);
    u16* W3t    = (u16*)alloc(32768 * 2);
    u16* Wp1t   = (u16*)alloc(16384 * 2);
    u16* Wp2t   = (u16*)alloc(16384 * 2);

    // part buffer: S=4 x NN x DD == S=8 x NN x EE (49.15 MB)
    float* part = (float*)alloc((size_t)4 * NN * DD * 4);
    const int KCH4 = 3008;   // S=4: 94/94/94/93 steps
    const int KCH8 = 1504;   // S=8: 47x7 + 46 steps (P3)

    prep_k<<<768, 256, 0, stream>>>(W1, W2, W3, Wp1, Wp2, W1t, W2t, W3t, Wp1t, Wp2t);

    // S1: xW1t[256][12000] = W1t @ x^T + b1
    gemm_k<64, 3, false, true, 1, false, true><<<4 * 188, 256, 0, stream>>>(
        W1t, x, xW1t, b1, DD, NN, DD, DD, DD, 4, 188, DD);

    // P1: part[s] = adj @ xW1 (fp32 adj nt-stream -> cvt_pk; dump bf16 adj)
    if (cacheAdj)
        pgemm_k<4, 3, true, true><<<188 * 4, 256, 0, stream>>>(
            adj, xW1t, part, adjb, NN, NN, NN, NN, 188, KCH4, 188 * 4 / 8);
    else
        pgemm_k<4, 3, true, false><<<188 * 4, 256, 0, stream>>>(
            adj, xW1t, part, nullptr, NN, NN, NN, NN, 188, KCH4, 188 * 4 / 8);

    // E1: h = relu(LN(t1 + x)) -> hbf (bf16) + hf32 (residual)
    ln_k<<<750, 256, 0, stream>>>(part, (long)NN * DD, 4, x, g1, be1, hbf, hf32, NN);

    // S2: hW2t = W2t @ h^T + b2
    gemm_k<64, 4, false, false, 1, false, true><<<4 * 188, 256, 0, stream>>>(
        W2t, hbf, hW2t, b2, DD, NN, DD, DD, DD, 4, 188, DD);

    // P2: part[s] = adj @ hW2 (bf16 adj nt-stream)
    if (cacheAdj)
        pgemm_k<4, 3, false, false><<<188 * 4, 256, 0, stream>>>(
            adjb, hW2t, part, nullptr, NN, NN, NN, NN, 188, KCH4, 188 * 4 / 8);
    else
        pgemm_k<4, 3, true, false><<<188 * 4, 256, 0, stream>>>(
            adj, hW2t, part, nullptr, NN, NN, NN, NN, 188, KCH4, 188 * 4 / 8);

    // E2: h2 = relu(LN(t2 + h))
    ln_k<<<750, 256, 0, stream>>>(part, (long)NN * DD, 4, hf32, g2, be2, h2bf, nullptr, NN);

    // S3: h2W3t[128][12000] = W3t @ h2^T + b3
    gemm_k<64, 4, false, false, 1, false, true><<<2 * 188, 256, 0, stream>>>(
        W3t, h2bf, h2W3t, b3, EE, NN, DD, DD, DD, 2, 188, DD);

    // P3: part[s] = adj @ h2W3 (S=8, 2-wave blocks for stream depth)
    if (cacheAdj)
        pgemm_k<2, 3, false, false><<<188 * 8, 128, 0, stream>>>(
            adjb, h2W3t, part, nullptr, NN, NN, NN, NN, 188, KCH8, 188 * 8 / 8);
    else
        pgemm_k<2, 3, true, false><<<188 * 8, 128, 0, stream>>>(
            adj, h2W3t, part, nullptr, NN, NN, NN, NN, 188, KCH8, 188 * 8 / 8);

    // E3: embedding out (fp32) + bf16 copy for proj head
    sum_k<<<1500, 256, 0, stream>>>(part, (long)NN * EE, 8, embOut, embbf, NN * EE / 4);

    // S4: p1 = relu(emb @ Wp1 + bp1)
    gemm_k<128, 4, false, false, 2, true, true><<<188, 256, 0, stream>>>(
        embbf, Wp1t, p1bf, bp1, NN, EE, EE, EE, EE, 188, 1, EE);

    // S5: z = p1 @ Wp2 + bp2 -> d_out (fp32)
    gemm_k<128, 4, false, false, 2, false, false><<<188, 256, 0, stream>>>(
        p1bf, Wp2t, zOut, bp2, NN, EE, EE, EE, EE, 188, 1, EE);
}

// Round 8
// 789.467 us; speedup vs baseline: 4.4778x; 4.4778x over previous
//
#include <hip/hip_runtime.h>

typedef unsigned short u16;
typedef unsigned int u32;
typedef __attribute__((ext_vector_type(8))) short bf16x8;
typedef __attribute__((ext_vector_type(8))) u16 u16x8;
typedef __attribute__((ext_vector_type(4))) u16 u16x4;
typedef __attribute__((ext_vector_type(4))) u32 u32x4;
typedef __attribute__((ext_vector_type(4))) float f32x4;

#define DEV static __device__ __forceinline__

DEV u16 f2bf(float f) {
    union { float f; u32 u; } v; v.f = f;
    u32 r = v.u + 0x7FFFu + ((v.u >> 16) & 1u);
    return (u16)(r >> 16);
}

DEV u32 cvtpk(float lo, float hi) {
    u32 r;
    asm("v_cvt_pk_bf16_f32 %0, %1, %2" : "=v"(r) : "v"(lo), "v"(hi));
    return r;
}

DEV void gload_lds16(const void* g, void* l) {
    __builtin_amdgcn_global_load_lds((const __attribute__((address_space(1))) void*)g,
                                     (__attribute__((address_space(3))) void*)l, 16, 0, 0);
}

// ---------------------------------------------------------------------------
// GEMM: C[M][N] = A[M][K] @ Bt[N][K]^T, row-major, K-contiguous tiles.
// BM=64, 256 threads = 4 waves (1x4), wave tile 64 x (BN/4).
// BK in {32,64}: K-step per barrier. Swizzle mask: BK=64 -> r&7 (128B rows =
// full bank wrap), BK=32 -> (r>>1)&3. Applied on BOTH staged source chunk and
// LDS read chunk (both-sides rule; gload_lds dest stays linear).
// AF32 (BK=64 only): A fp32 -> reg issue + cvt_pk commit (split around MFMA).
// BF32 (BK=32 only): B fp32 -> reg issue + cvt commit (S1).
// DUMPA: commit also nt-stores the bf16 A tile (exact once-cover).
// Tail: last step may be 32 wide (lt); invalid chunks clamp to k0, MFMA kk
// loop runs lt/32 sub-steps.
// ---------------------------------------------------------------------------
template<int BN, int BK, int MINW, bool AF32, bool BF32, bool DUMPA, int BIAS, bool RELU, bool OUTBF>
__global__ __launch_bounds__(256, MINW) void gemm_k(
    const void* __restrict__ Ap, const void* __restrict__ Bp, void* __restrict__ Cp,
    u16* __restrict__ Adump, const float* __restrict__ bias,
    int M, int N, int K, int lda, int ldb, int nRT, int nNT, int KCH)
{
    constexpr int BM = 64;
    constexpr int WN = BN / 4;
    constexpr int FI = 4, FJ = WN / 16;
    constexpr int CH = BK / 8;                 // 16B chunks per row
    constexpr int CPTA = (BM * CH) / 256;      // A chunks per thread
    constexpr int CPTB = (BN * CH) / 256;      // B chunks per thread
    __shared__ u16 ldsA[2][BM * BK];
    __shared__ u16 ldsB[2][BN * BK];

    const int tid = threadIdx.x;
    int bid = blockIdx.x;
    const int rt = bid % nRT; bid /= nRT;
    const int nt = bid % nNT;
    const int s  = bid / nNT;
    const int m0 = rt * BM, n0 = nt * BN;
    const int kBeg = s * KCH;
    const int kEnd = (K < kBeg + KCH) ? K : (kBeg + KCH);
    const int nsteps = (kEnd - kBeg + BK - 1) / BK;

    const int w = tid >> 6, l = tid & 63;
    const int wn = w * WN;
    const int lr = l & 15, lg = l >> 4;

    f32x4 acc[FI][FJ] = {};
    f32x4 Rf[4];           // AF32 issue regs (BK=64: 16 fp32/thread)
    float bR[8];           // BF32 issue regs (BK=32)

    auto mask_of = [](int r) { return (BK == 64) ? (r & 7) : ((r >> 1) & 3); };

    auto aIssueB = [&](int buf, int k0, int len) {
        if constexpr (AF32) {
            int r = tid >> 2, qf = tid & 3;
            int gm = m0 + r; gm = (gm < M) ? gm : (M - 1);
            int kc = (qf * 16 < len) ? (k0 + qf * 16) : k0;
            const f32x4* p = (const f32x4*)((const float*)Ap + (size_t)gm * lda + kc);
            Rf[0] = __builtin_nontemporal_load(p);
            Rf[1] = __builtin_nontemporal_load(p + 1);
            Rf[2] = __builtin_nontemporal_load(p + 2);
            Rf[3] = __builtin_nontemporal_load(p + 3);
            (void)buf;
        } else {
            const u16* A = (const u16*)Ap;
            #pragma unroll
            for (int u = 0; u < CPTA; u++) {
                int slot = u * 256 + tid;
                int r = slot / CH, c = slot % CH;
                int q = c ^ mask_of(r);
                int gm = m0 + r; gm = (gm < M) ? gm : (M - 1);
                int kc = (q * 8 < len) ? (k0 + q * 8) : k0;
                gload_lds16(A + (size_t)gm * lda + kc, &ldsA[buf][slot * 8]);
            }
        }
    };
    auto aCommit = [&](int buf, int k0, int len) {
        if constexpr (AF32) {
            int r = tid >> 2, qf = tid & 3;
            u32x4 pk0, pk1;
            pk0[0] = cvtpk(Rf[0][0], Rf[0][1]); pk0[1] = cvtpk(Rf[0][2], Rf[0][3]);
            pk0[2] = cvtpk(Rf[1][0], Rf[1][1]); pk0[3] = cvtpk(Rf[1][2], Rf[1][3]);
            pk1[0] = cvtpk(Rf[2][0], Rf[2][1]); pk1[1] = cvtpk(Rf[2][2], Rf[2][3]);
            pk1[2] = cvtpk(Rf[3][0], Rf[3][1]); pk1[3] = cvtpk(Rf[3][2], Rf[3][3]);
            int mk = mask_of(r);
            *(u32x4*)&ldsA[buf][r * BK + ((qf * 2) ^ mk) * 8]     = pk0;
            *(u32x4*)&ldsA[buf][r * BK + ((qf * 2 + 1) ^ mk) * 8] = pk1;
            if constexpr (DUMPA) {
                if (m0 + r < M && qf * 16 < len) {
                    u16* d = Adump + (size_t)(m0 + r) * lda + k0 + qf * 16;
                    __builtin_nontemporal_store(pk0, (u32x4*)d);
                    __builtin_nontemporal_store(pk1, (u32x4*)(d + 8));
                }
            }
        }
    };
    auto bIssue = [&](int buf, int k0, int len) {
        if constexpr (BF32) {
            const float* B = (const float*)Bp;
            int r = tid >> 2, q = tid & 3;
            int gn = n0 + r; gn = (gn < N) ? gn : (N - 1);
            const float4* src = (const float4*)(B + (size_t)gn * ldb + k0 + q * 8);
            float4 v0 = src[0], v1 = src[1];
            bR[0]=v0.x; bR[1]=v0.y; bR[2]=v0.z; bR[3]=v0.w;
            bR[4]=v1.x; bR[5]=v1.y; bR[6]=v1.z; bR[7]=v1.w;
            (void)buf; (void)len;
        } else {
            const u16* B = (const u16*)Bp;
            #pragma unroll
            for (int u = 0; u < CPTB; u++) {
                int slot = u * 256 + tid;
                int r = slot / CH, c = slot % CH;
                int q = c ^ mask_of(r);
                int gn = n0 + r; gn = (gn < N) ? gn : (N - 1);
                int kc = (q * 8 < len) ? (k0 + q * 8) : k0;
                gload_lds16(B + (size_t)gn * ldb + kc, &ldsB[buf][slot * 8]);
            }
        }
    };
    auto bCommit = [&](int buf) {
        if constexpr (BF32) {
            int r = tid >> 2, q = tid & 3;
            u16x8 pk;
            #pragma unroll
            for (int e = 0; e < 8; e++) pk[e] = f2bf(bR[e]);
            *(u16x8*)&ldsB[buf][r * BK + (q ^ mask_of(r)) * 8] = pk;
        }
    };

    int len0 = kEnd - kBeg; if (len0 > BK) len0 = BK;
    aIssueB(0, kBeg, len0); bIssue(0, kBeg, len0);
    aCommit(0, kBeg, len0); bCommit(0);
    __syncthreads();

    for (int t = 0; t < nsteps; t++) {
        const int k0 = kBeg + t * BK;
        int lt = kEnd - k0; if (lt > BK) lt = BK;
        const int cur = t & 1, nxt = cur ^ 1;
        const bool hasNext = (t + 1 < nsteps);
        int kn = k0 + BK;
        int ln = kEnd - kn; if (ln > BK) ln = BK;
        if (hasNext) { aIssueB(nxt, kn, ln); bIssue(nxt, kn, ln); }

        #pragma unroll
        for (int kk = 0; kk < BK / 32; kk++) {
            if (kk * 32 < lt) {
                bf16x8 af[FI], bfr[FJ];
                #pragma unroll
                for (int i = 0; i < FI; i++) {
                    int r = i * 16 + lr;
                    af[i] = *(const bf16x8*)&ldsA[cur][r * BK + ((kk * 4 + lg) ^ mask_of(r)) * 8];
                }
                #pragma unroll
                for (int j = 0; j < FJ; j++) {
                    int r = wn + j * 16 + lr;
                    bfr[j] = *(const bf16x8*)&ldsB[cur][r * BK + ((kk * 4 + lg) ^ mask_of(r)) * 8];
                }
                #pragma unroll
                for (int i = 0; i < FI; i++)
                    #pragma unroll
                    for (int j = 0; j < FJ; j++)
                        acc[i][j] = __builtin_amdgcn_mfma_f32_16x16x32_bf16(af[i], bfr[j], acc[i][j], 0, 0, 0);
            }
        }

        if (hasNext) { aCommit(nxt, kn, ln); bCommit(nxt); }
        __syncthreads();
    }

    #pragma unroll
    for (int i = 0; i < FI; i++)
        #pragma unroll
        for (int j = 0; j < FJ; j++)
            #pragma unroll
            for (int e = 0; e < 4; e++) {
                int row = m0 + i * 16 + lg * 4 + e;
                int col = n0 + wn + j * 16 + lr;
                if (row < M && col < N) {
                    float v = acc[i][j][e];
                    if constexpr (BIAS == 1) v += bias[row];
                    if constexpr (BIAS == 2) v += bias[col];
                    if constexpr (RELU) v = fmaxf(v, 0.0f);
                    if constexpr (OUTBF) ((u16*)Cp)[(size_t)row * N + col] = f2bf(v);
                    else ((float*)Cp)[(size_t)s * M * N + (size_t)row * N + col] = v;
                }
            }
}

// fused: sum split-K partials + residual -> LayerNorm -> relu -> bf16 (+f32) out. D=256.
__global__ __launch_bounds__(256) void ln_k(
    const float* __restrict__ part, long pStride, int nPart,
    const float* __restrict__ resid, const float* __restrict__ gamma, const float* __restrict__ beta,
    u16* __restrict__ obf, float* __restrict__ of32, int M)
{
    const int w = threadIdx.x >> 6, l = threadIdx.x & 63;
    for (int row = blockIdx.x * 4 + w; row < M; row += gridDim.x * 4) {
        size_t base = (size_t)row * 256 + l * 4;
        float4 v = *(const float4*)(part + base);
        for (int s = 1; s < nPart; s++) {
            float4 u = *(const float4*)(part + (size_t)s * pStride + base);
            v.x += u.x; v.y += u.y; v.z += u.z; v.w += u.w;
        }
        float4 r = *(const float4*)(resid + base);
        v.x += r.x; v.y += r.y; v.z += r.z; v.w += r.w;
        float sum = v.x + v.y + v.z + v.w;
        float sq  = v.x*v.x + v.y*v.y + v.z*v.z + v.w*v.w;
        #pragma unroll
        for (int o = 32; o >= 1; o >>= 1) {
            sum += __shfl_xor(sum, o, 64);
            sq  += __shfl_xor(sq, o, 64);
        }
        float mu  = sum * (1.0f / 256.0f);
        float var = sq * (1.0f / 256.0f) - mu * mu;
        float sc  = rsqrtf(var + 1e-5f);
        int c = l * 4;
        float y0 = fmaxf((v.x - mu) * sc * gamma[c + 0] + beta[c + 0], 0.0f);
        float y1 = fmaxf((v.y - mu) * sc * gamma[c + 1] + beta[c + 1], 0.0f);
        float y2 = fmaxf((v.z - mu) * sc * gamma[c + 2] + beta[c + 2], 0.0f);
        float y3 = fmaxf((v.w - mu) * sc * gamma[c + 3] + beta[c + 3], 0.0f);
        u16x4 pk; pk[0] = f2bf(y0); pk[1] = f2bf(y1); pk[2] = f2bf(y2); pk[3] = f2bf(y3);
        *(u16x4*)(obf + base) = pk;
        if (of32) { float4 o4; o4.x = y0; o4.y = y1; o4.z = y2; o4.w = y3; *(float4*)(of32 + base) = o4; }
    }
}

// sum split-K partials -> f32 out + bf16 copy (embedding)
__global__ __launch_bounds__(256) void sum_k(
    const float* __restrict__ p, long pStride, int nPart,
    float* __restrict__ of, u16* __restrict__ ob, int total4)
{
    int i = blockIdx.x * 256 + threadIdx.x;
    if (i >= total4) return;
    size_t b = (size_t)i * 4;
    float4 v = *(const float4*)(p + b);
    for (int s = 1; s < nPart; s++) {
        float4 u = *(const float4*)(p + (size_t)s * pStride + b);
        v.x += u.x; v.y += u.y; v.z += u.z; v.w += u.w;
    }
    *(float4*)(of + b) = v;
    u16x4 pk; pk[0] = f2bf(v.x); pk[1] = f2bf(v.y); pk[2] = f2bf(v.z); pk[3] = f2bf(v.w);
    *(u16x4*)(ob + b) = pk;
}

// transpose + bf16-convert the 5 weight matrices.
__global__ __launch_bounds__(256) void prep_k(
    const float* __restrict__ s0, const float* __restrict__ s1, const float* __restrict__ s2,
    const float* __restrict__ s3, const float* __restrict__ s4,
    u16* __restrict__ d0, u16* __restrict__ d1, u16* __restrict__ d2,
    u16* __restrict__ d3, u16* __restrict__ d4)
{
    int i = blockIdx.x * 256 + threadIdx.x;
    if (i < 65536) {
        int o = i >> 8, ii = i & 255; d0[i] = f2bf(s0[(size_t)ii * 256 + o]);
    } else if (i < 131072) {
        int j = i - 65536; int o = j >> 8, ii = j & 255; d1[j] = f2bf(s1[(size_t)ii * 256 + o]);
    } else if (i < 163840) {
        int j = i - 131072; int o = j >> 8, ii = j & 255; d2[j] = f2bf(s2[(size_t)ii * 128 + o]);
    } else if (i < 180224) {
        int j = i - 163840; int o = j >> 7, ii = j & 127; d3[j] = f2bf(s3[(size_t)ii * 128 + o]);
    } else if (i < 196608) {
        int j = i - 180224; int o = j >> 7, ii = j & 127; d4[j] = f2bf(s4[(size_t)ii * 128 + o]);
    }
}

extern "C" void kernel_launch(void* const* d_in, const int* in_sizes, int n_in,
                              void* d_out, int out_size, void* d_ws, size_t ws_size,
                              hipStream_t stream)
{
    if (n_in < 16) return;
    const int NN = 12000, DD = 256, EE = 128;
    const float* x   = (const float*)d_in[0];
    const float* adj = (const float*)d_in[1];
    const float* W1  = (const float*)d_in[2];
    const float* b1  = (const float*)d_in[3];
    const float* g1  = (const float*)d_in[4];
    const float* be1 = (const float*)d_in[5];
    const float* W2  = (const float*)d_in[6];
    const float* b2  = (const float*)d_in[7];
    const float* g2  = (const float*)d_in[8];
    const float* be2 = (const float*)d_in[9];
    const float* W3  = (const float*)d_in[10];
    const float* b3  = (const float*)d_in[11];
    const float* Wp1 = (const float*)d_in[12];
    const float* bp1 = (const float*)d_in[13];
    const float* Wp2 = (const float*)d_in[14];
    const float* bp2 = (const float*)d_in[15];
    float* zOut   = (float*)d_out;
    float* embOut = zOut + (size_t)NN * EE;

    char* ws = (char*)d_ws;
    size_t off = 0;
    auto alloc = [&](size_t bytes) -> void* {
        off = (off + 255) & ~(size_t)255;
        void* p = ws + off; off += bytes; return p;
    };

    const size_t adjElems = (size_t)NN * NN;
    bool cacheAdj = ws_size >= adjElems * 2 + 100000000ULL;
    u16* adjb = cacheAdj ? (u16*)alloc(adjElems * 2) : nullptr;

    u16* xW1t   = (u16*)alloc((size_t)DD * NN * 2);
    u16* hW2t   = (u16*)alloc((size_t)DD * NN * 2);
    u16* h2W3t  = (u16*)alloc((size_t)EE * NN * 2);
    u16* hbf    = (u16*)alloc((size_t)NN * DD * 2);
    float* hf32 = (float*)alloc((size_t)NN * DD * 4);
    u16* h2bf   = (u16*)alloc((size_t)NN * DD * 2);
    u16* embbf  = (u16*)alloc((size_t)NN * EE * 2);
    u16* p1bf   = (u16*)alloc((size_t)NN * EE * 2);
    u16* W1t    = (u16*)alloc(65536 * 2);
    u16* W2t    = (u16*)alloc(65536 * 2);
    u16* W3t    = (u16*)alloc(32768 * 2);
    u16* Wp1t   = (u16*)alloc(16384 * 2);
    u16* Wp2t   = (u16*)alloc(16384 * 2);

    const int S = 4;
    float* part = (float*)alloc((size_t)S * NN * DD * 4);
    const int KCH = 3008;   // chunks 0-2: 47x64 steps; chunk 3: 46x64 + 32 tail

    prep_k<<<768, 256, 0, stream>>>(W1, W2, W3, Wp1, Wp2, W1t, W2t, W3t, Wp1t, Wp2t);

    // S1: xW1t[256][12000] = W1t @ x^T + b1 (BK=32, fp32 B reg-staged)
    gemm_k<64, 32, 3, false, true, false, 1, false, true><<<4 * 188, 256, 0, stream>>>(
        W1t, x, xW1t, nullptr, b1, DD, NN, DD, DD, DD, 4, 188, DD);

    // P1: part[s] = adj @ xW1 (BK=64; fp32 adj nt-load + cvt; dump bf16 adj)
    if (cacheAdj)
        gemm_k<256, 64, 2, true, false, true, 0, false, false><<<188 * S, 256, 0, stream>>>(
            adj, xW1t, part, adjb, nullptr, NN, DD, NN, NN, NN, 188, 1, KCH);
    else
        gemm_k<256, 64, 2, true, false, false, 0, false, false><<<188 * S, 256, 0, stream>>>(
            adj, xW1t, part, nullptr, nullptr, NN, DD, NN, NN, NN, 188, 1, KCH);

    // E1: h = relu(LN(t1 + x)) -> hbf (bf16) + hf32 (residual)
    ln_k<<<750, 256, 0, stream>>>(part, (long)NN * DD, S, x, g1, be1, hbf, hf32, NN);

    // S2: hW2t = W2t @ h^T + b2
    gemm_k<64, 32, 4, false, false, false, 1, false, true><<<4 * 188, 256, 0, stream>>>(
        W2t, hbf, hW2t, nullptr, b2, DD, NN, DD, DD, DD, 4, 188, DD);

    // P2: part[s] = adj @ hW2 (BK=64, bf16 adj via gload_lds)
    if (cacheAdj)
        gemm_k<256, 64, 2, false, false, false, 0, false, false><<<188 * S, 256, 0, stream>>>(
            adjb, hW2t, part, nullptr, nullptr, NN, DD, NN, NN, NN, 188, 1, KCH);
    else
        gemm_k<256, 64, 2, true, false, false, 0, false, false><<<188 * S, 256, 0, stream>>>(
            adj, hW2t, part, nullptr, nullptr, NN, DD, NN, NN, NN, 188, 1, KCH);

    // E2: h2 = relu(LN(t2 + h))
    ln_k<<<750, 256, 0, stream>>>(part, (long)NN * DD, S, hf32, g2, be2, h2bf, nullptr, NN);

    // S3: h2W3t[128][12000] = W3t @ h2^T + b3
    gemm_k<64, 32, 4, false, false, false, 1, false, true><<<2 * 188, 256, 0, stream>>>(
        W3t, h2bf, h2W3t, nullptr, b3, EE, NN, DD, DD, DD, 2, 188, DD);

    // P3: part[s] = adj @ h2W3 (BK=64, BN=128, 3 blocks/CU)
    if (cacheAdj)
        gemm_k<128, 64, 3, false, false, false, 0, false, false><<<188 * S, 256, 0, stream>>>(
            adjb, h2W3t, part, nullptr, nullptr, NN, EE, NN, NN, NN, 188, 1, KCH);
    else
        gemm_k<128, 64, 3, true, false, false, 0, false, false><<<188 * S, 256, 0, stream>>>(
            adj, h2W3t, part, nullptr, nullptr, NN, EE, NN, NN, NN, 188, 1, KCH);

    // E3: embedding out (fp32) + bf16 copy for proj head
    sum_k<<<1500, 256, 0, stream>>>(part, (long)NN * EE, S, embOut, embbf, NN * EE / 4);

    // S4: p1 = relu(emb @ Wp1 + bp1)
    gemm_k<128, 32, 4, false, false, false, 2, true, true><<<188, 256, 0, stream>>>(
        embbf, Wp1t, p1bf, nullptr, bp1, NN, EE, EE, EE, EE, 188, 1, EE);

    // S5: z = p1 @ Wp2 + bp2 -> d_out (fp32)
    gemm_k<128, 32, 4, false, false, false, 2, false, false><<<188, 256, 0, stream>>>(
        p1bf, Wp2t, zOut, nullptr, bp2, NN, EE, EE, EE, EE, 188, 1, EE);
}

// Round 9
// 701.415 us; speedup vs baseline: 5.0399x; 1.1255x over previous
//
#include <hip/hip_runtime.h>

typedef unsigned short u16;
typedef unsigned int u32;
typedef __attribute__((ext_vector_type(8))) short bf16x8;
typedef __attribute__((ext_vector_type(8))) u16 u16x8;
typedef __attribute__((ext_vector_type(4))) u16 u16x4;
typedef __attribute__((ext_vector_type(4))) float f32x4;

#define DEV static __device__ __forceinline__

DEV u16 f2bf(float f) {
    union { float f; u32 u; } v; v.f = f;
    u32 r = v.u + 0x7FFFu + ((v.u >> 16) & 1u);
    return (u16)(r >> 16);
}

DEV int swzc(int r, int c) { return c ^ ((r >> 1) & 3); }

DEV void gload_lds16(const void* g, void* l) {
    __builtin_amdgcn_global_load_lds((const __attribute__((address_space(1))) void*)g,
                                     (__attribute__((address_space(3))) void*)l, 16, 0, 0);
}

template<int N> DEV void waitcnt_vm() {
    if constexpr (N == 0) asm volatile("s_waitcnt vmcnt(0) lgkmcnt(0)" ::: "memory");
    else if constexpr (N == 3) asm volatile("s_waitcnt vmcnt(3) lgkmcnt(0)" ::: "memory");
    else if constexpr (N == 5) asm volatile("s_waitcnt vmcnt(5) lgkmcnt(0)" ::: "memory");
}

// ---------------------------------------------------------------------------
// Counted-vmcnt adjacency pass (P2/P3): C_part[s][M][BN] = Ab[M][K] @ Bt[BN][K]^T.
// bf16 A and B staged via global_load_lds into 3-deep LDS buffers.
// Per iteration: issue stage(t+2), compute tile t, then
//   s_waitcnt vmcnt(NLOADS) lgkmcnt(0); s_barrier; sched_barrier(0)
// -> stage(t+1) drained (ready for next iter), stage(t+2) RIDES THROUGH the
// barrier (T3+T4: never drain vmcnt to 0 in the main loop).
// BK=32, 4 waves 1x4, wave tile 64 x (BN/4). NLOADS = per-thread loads/tile.
// ---------------------------------------------------------------------------
template<int BN, int MINW, int NLOADS>
__global__ __launch_bounds__(256, MINW) void padj_k(
    const u16* __restrict__ Ab, const u16* __restrict__ Bt, float* __restrict__ Cp,
    int M, int K, int lda, int ldb, int nRT, int KCH)
{
    constexpr int BM = 64, BK = 32;
    constexpr int WN = BN / 4, FJ = WN / 16;
    constexpr int CPTB = BN / 64;
    __shared__ u16 ldsA[3][BM * BK];
    __shared__ u16 ldsB[3][BN * BK];

    const int tid = threadIdx.x;
    const int bid = blockIdx.x;
    const int rt = bid % nRT;
    const int s  = bid / nRT;
    const int m0 = rt * BM;
    const int kBeg = s * KCH;
    const int kEnd = (K < kBeg + KCH) ? K : (kBeg + KCH);
    const int nsteps = (kEnd - kBeg) >> 5;

    const int w = tid >> 6, l = tid & 63;
    const int wn = w * WN;
    const int lr = l & 15, lg = l >> 4;

    // A staging map: 1 chunk/thread
    const int ar = tid >> 2, ac = tid & 3;
    int gmA = m0 + ar; if (gmA > M - 1) gmA = M - 1;
    const size_t aoff = (size_t)gmA * lda + swzc(ar, ac) * 8;
    // B staging map: CPTB chunks/thread
    size_t boff[CPTB];
    #pragma unroll
    for (int u = 0; u < CPTB; u++) {
        int slot = u * 256 + tid;
        int r = slot >> 2, c = slot & 3;
        boff[u] = (size_t)r * ldb + swzc(r, c) * 8;
    }

    f32x4 acc[4][FJ] = {};

    auto stage = [&](int buf, int k0) {
        gload_lds16(Ab + aoff + k0, &ldsA[buf][tid * 8]);
        #pragma unroll
        for (int u = 0; u < CPTB; u++)
            gload_lds16(Bt + boff[u] + k0, &ldsB[buf][(u * 256 + tid) * 8]);
    };

    stage(0, kBeg);
    if (nsteps > 1) stage(1, kBeg + 32);
    if (nsteps > 1) waitcnt_vm<NLOADS>(); else waitcnt_vm<0>();
    __builtin_amdgcn_s_barrier();
    __builtin_amdgcn_sched_barrier(0);

    for (int t = 0; t < nsteps; t++) {
        const int cur = t % 3;
        const bool deep = (t + 2 < nsteps);
        if (deep) stage((t + 2) % 3, kBeg + (t + 2) * 32);

        bf16x8 af[4], bf[FJ];
        #pragma unroll
        for (int i = 0; i < 4; i++) {
            int r = i * 16 + lr;
            af[i] = *(const bf16x8*)&ldsA[cur][r * BK + swzc(r, lg) * 8];
        }
        #pragma unroll
        for (int j = 0; j < FJ; j++) {
            int r = wn + j * 16 + lr;
            bf[j] = *(const bf16x8*)&ldsB[cur][r * BK + swzc(r, lg) * 8];
        }
        #pragma unroll
        for (int i = 0; i < 4; i++)
            #pragma unroll
            for (int j = 0; j < FJ; j++)
                acc[i][j] = __builtin_amdgcn_mfma_f32_16x16x32_bf16(af[i], bf[j], acc[i][j], 0, 0, 0);

        if (deep) waitcnt_vm<NLOADS>(); else waitcnt_vm<0>();
        __builtin_amdgcn_s_barrier();
        __builtin_amdgcn_sched_barrier(0);
    }

    float* Cbase = Cp + (size_t)s * M * BN;
    #pragma unroll
    for (int i = 0; i < 4; i++)
        #pragma unroll
        for (int j = 0; j < FJ; j++)
            #pragma unroll
            for (int e = 0; e < 4; e++) {
                int row = m0 + i * 16 + lg * 4 + e;
                int col = wn + j * 16 + lr;
                if (row < M) Cbase[(size_t)row * BN + col] = acc[i][j][e];
            }
}

// ---------------------------------------------------------------------------
// Small-GEMM + P1 kernel: BK=32 LDS double-buffer (r3 structure, verified 665us).
// ---------------------------------------------------------------------------
template<int BN, int MINW, bool AF32, bool BF32, bool DUMPA, int BIAS, bool RELU, bool OUTBF>
__global__ __launch_bounds__(256, MINW) void gemm_k(
    const void* __restrict__ Ap, const void* __restrict__ Bp, void* __restrict__ Cp,
    u16* __restrict__ Adump, const float* __restrict__ bias,
    int M, int N, int K, int lda, int ldb, int nRT, int nNT, int KCH)
{
    constexpr int BM = 64;
    constexpr int WN = BN / 4;
    constexpr int FI = 4;
    constexpr int FJ = WN / 16;
    constexpr int CPT = BN / 64;
    __shared__ u16 ldsA[2][BM * 32];
    __shared__ u16 ldsB[2][BN * 32];

    const int tid = threadIdx.x;
    int bid = blockIdx.x;
    const int rt = bid % nRT; bid /= nRT;
    const int nt = bid % nNT;
    const int s  = bid / nNT;
    const int m0 = rt * BM, n0 = nt * BN;
    const int kBeg = s * KCH;
    const int kEnd = (K < kBeg + KCH) ? K : (kBeg + KCH);
    const int nsteps = (kEnd - kBeg) >> 5;

    const int w = tid >> 6, l = tid & 63;
    const int wn = w * WN;
    const int lr = l & 15, lg = l >> 4;

    f32x4 acc[FI][FJ] = {};
    float aR[8], bR[8];

    auto aIssue = [&](int buf, int k0) {
        if constexpr (AF32) {
            const float* A = (const float*)Ap;
            int r = tid >> 2, q = tid & 3;
            int gm = m0 + r; gm = (gm < M) ? gm : (M - 1);
            const float4* src = (const float4*)(A + (size_t)gm * lda + k0 + q * 8);
            float4 v0 = src[0], v1 = src[1];
            aR[0]=v0.x; aR[1]=v0.y; aR[2]=v0.z; aR[3]=v0.w;
            aR[4]=v1.x; aR[5]=v1.y; aR[6]=v1.z; aR[7]=v1.w;
            (void)buf;
        } else {
            const u16* A = (const u16*)Ap;
            int r = tid >> 2, cs = tid & 3;
            int c = swzc(r, cs);
            int gm = m0 + r; gm = (gm < M) ? gm : (M - 1);
            gload_lds16(A + (size_t)gm * lda + k0 + c * 8, &ldsA[buf][tid * 8]);
        }
    };
    auto aCommit = [&](int buf, int k0) {
        if constexpr (AF32) {
            int r = tid >> 2, q = tid & 3;
            u16x8 pk;
            #pragma unroll
            for (int e = 0; e < 8; e++) pk[e] = f2bf(aR[e]);
            *(u16x8*)&ldsA[buf][r * 32 + swzc(r, q) * 8] = pk;
            if constexpr (DUMPA) {
                int gm = m0 + r;
                if (gm < M) *(u16x8*)(Adump + (size_t)gm * lda + k0 + q * 8) = pk;
            }
        }
    };
    auto bIssue = [&](int buf, int k0) {
        if constexpr (BF32) {
            const float* B = (const float*)Bp;
            int r = tid >> 2, q = tid & 3;
            int gn = n0 + r; gn = (gn < N) ? gn : (N - 1);
            const float4* src = (const float4*)(B + (size_t)gn * ldb + k0 + q * 8);
            float4 v0 = src[0], v1 = src[1];
            bR[0]=v0.x; bR[1]=v0.y; bR[2]=v0.z; bR[3]=v0.w;
            bR[4]=v1.x; bR[5]=v1.y; bR[6]=v1.z; bR[7]=v1.w;
            (void)buf;
        } else {
            const u16* B = (const u16*)Bp;
            #pragma unroll
            for (int u = 0; u < CPT; u++) {
                int slot = u * 256 + tid;
                int r = slot >> 2, cs = slot & 3;
                int c = swzc(r, cs);
                int gn = n0 + r; gn = (gn < N) ? gn : (N - 1);
                gload_lds16(B + (size_t)gn * ldb + k0 + c * 8, &ldsB[buf][slot * 8]);
            }
        }
    };
    auto bCommit = [&](int buf) {
        if constexpr (BF32) {
            int r = tid >> 2, q = tid & 3;
            u16x8 pk;
            #pragma unroll
            for (int e = 0; e < 8; e++) pk[e] = f2bf(bR[e]);
            *(u16x8*)&ldsB[buf][r * 32 + swzc(r, q) * 8] = pk;
        }
    };

    aIssue(0, kBeg); bIssue(0, kBeg);
    aCommit(0, kBeg); bCommit(0);
    __syncthreads();

    for (int t = 0; t < nsteps; t++) {
        const int k = kBeg + t * 32;
        const int cur = t & 1, nxt = cur ^ 1;
        if (t + 1 < nsteps) { aIssue(nxt, k + 32); bIssue(nxt, k + 32); }

        bf16x8 af[FI], bfr[FJ];
        #pragma unroll
        for (int i = 0; i < FI; i++) {
            int r = i * 16 + lr;
            af[i] = *(const bf16x8*)&ldsA[cur][r * 32 + swzc(r, lg) * 8];
        }
        #pragma unroll
        for (int j = 0; j < FJ; j++) {
            int r = wn + j * 16 + lr;
            bfr[j] = *(const bf16x8*)&ldsB[cur][r * 32 + swzc(r, lg) * 8];
        }
        #pragma unroll
        for (int i = 0; i < FI; i++)
            #pragma unroll
            for (int j = 0; j < FJ; j++)
                acc[i][j] = __builtin_amdgcn_mfma_f32_16x16x32_bf16(af[i], bfr[j], acc[i][j], 0, 0, 0);

        if (t + 1 < nsteps) { aCommit(nxt, k + 32); bCommit(nxt); }
        __syncthreads();
    }

    #pragma unroll
    for (int i = 0; i < FI; i++)
        #pragma unroll
        for (int j = 0; j < FJ; j++)
            #pragma unroll
            for (int e = 0; e < 4; e++) {
                int row = m0 + i * 16 + lg * 4 + e;
                int col = n0 + wn + j * 16 + lr;
                if (row < M && col < N) {
                    float v = acc[i][j][e];
                    if constexpr (BIAS == 1) v += bias[row];
                    if constexpr (BIAS == 2) v += bias[col];
                    if constexpr (RELU) v = fmaxf(v, 0.0f);
                    if constexpr (OUTBF) ((u16*)Cp)[(size_t)row * N + col] = f2bf(v);
                    else ((float*)Cp)[(size_t)s * M * N + (size_t)row * N + col] = v;
                }
            }
}

// fused: sum split-K partials + residual -> LayerNorm -> relu -> bf16 (+f32) out. D=256.
__global__ __launch_bounds__(256) void ln_k(
    const float* __restrict__ part, long pStride, int nPart,
    const float* __restrict__ resid, const float* __restrict__ gamma, const float* __restrict__ beta,
    u16* __restrict__ obf, float* __restrict__ of32, int M)
{
    const int w = threadIdx.x >> 6, l = threadIdx.x & 63;
    for (int row = blockIdx.x * 4 + w; row < M; row += gridDim.x * 4) {
        size_t base = (size_t)row * 256 + l * 4;
        float4 v = *(const float4*)(part + base);
        for (int s = 1; s < nPart; s++) {
            float4 u = *(const float4*)(part + (size_t)s * pStride + base);
            v.x += u.x; v.y += u.y; v.z += u.z; v.w += u.w;
        }
        float4 r = *(const float4*)(resid + base);
        v.x += r.x; v.y += r.y; v.z += r.z; v.w += r.w;
        float sum = v.x + v.y + v.z + v.w;
        float sq  = v.x*v.x + v.y*v.y + v.z*v.z + v.w*v.w;
        #pragma unroll
        for (int o = 32; o >= 1; o >>= 1) {
            sum += __shfl_xor(sum, o, 64);
            sq  += __shfl_xor(sq, o, 64);
        }
        float mu  = sum * (1.0f / 256.0f);
        float var = sq * (1.0f / 256.0f) - mu * mu;
        float sc  = rsqrtf(var + 1e-5f);
        int c = l * 4;
        float y0 = fmaxf((v.x - mu) * sc * gamma[c + 0] + beta[c + 0], 0.0f);
        float y1 = fmaxf((v.y - mu) * sc * gamma[c + 1] + beta[c + 1], 0.0f);
        float y2 = fmaxf((v.z - mu) * sc * gamma[c + 2] + beta[c + 2], 0.0f);
        float y3 = fmaxf((v.w - mu) * sc * gamma[c + 3] + beta[c + 3], 0.0f);
        u16x4 pk; pk[0] = f2bf(y0); pk[1] = f2bf(y1); pk[2] = f2bf(y2); pk[3] = f2bf(y3);
        *(u16x4*)(obf + base) = pk;
        if (of32) { float4 o4; o4.x = y0; o4.y = y1; o4.z = y2; o4.w = y3; *(float4*)(of32 + base) = o4; }
    }
}

// sum split-K partials -> f32 out + bf16 copy (embedding)
__global__ __launch_bounds__(256) void sum_k(
    const float* __restrict__ p, long pStride, int nPart,
    float* __restrict__ of, u16* __restrict__ ob, int total4)
{
    int i = blockIdx.x * 256 + threadIdx.x;
    if (i >= total4) return;
    size_t b = (size_t)i * 4;
    float4 v = *(const float4*)(p + b);
    for (int s = 1; s < nPart; s++) {
        float4 u = *(const float4*)(p + (size_t)s * pStride + b);
        v.x += u.x; v.y += u.y; v.z += u.z; v.w += u.w;
    }
    *(float4*)(of + b) = v;
    u16x4 pk; pk[0] = f2bf(v.x); pk[1] = f2bf(v.y); pk[2] = f2bf(v.z); pk[3] = f2bf(v.w);
    *(u16x4*)(ob + b) = pk;
}

// transpose + bf16-convert the 5 weight matrices.
__global__ __launch_bounds__(256) void prep_k(
    const float* __restrict__ s0, const float* __restrict__ s1, const float* __restrict__ s2,
    const float* __restrict__ s3, const float* __restrict__ s4,
    u16* __restrict__ d0, u16* __restrict__ d1, u16* __restrict__ d2,
    u16* __restrict__ d3, u16* __restrict__ d4)
{
    int i = blockIdx.x * 256 + threadIdx.x;
    if (i < 65536) {
        int o = i >> 8, ii = i & 255; d0[i] = f2bf(s0[(size_t)ii * 256 + o]);
    } else if (i < 131072) {
        int j = i - 65536; int o = j >> 8, ii = j & 255; d1[j] = f2bf(s1[(size_t)ii * 256 + o]);
    } else if (i < 163840) {
        int j = i - 131072; int o = j >> 8, ii = j & 255; d2[j] = f2bf(s2[(size_t)ii * 128 + o]);
    } else if (i < 180224) {
        int j = i - 163840; int o = j >> 7, ii = j & 127; d3[j] = f2bf(s3[(size_t)ii * 128 + o]);
    } else if (i < 196608) {
        int j = i - 180224; int o = j >> 7, ii = j & 127; d4[j] = f2bf(s4[(size_t)ii * 128 + o]);
    }
}

extern "C" void kernel_launch(void* const* d_in, const int* in_sizes, int n_in,
                              void* d_out, int out_size, void* d_ws, size_t ws_size,
                              hipStream_t stream)
{
    if (n_in < 16) return;
    const int NN = 12000, DD = 256, EE = 128;
    const float* x   = (const float*)d_in[0];
    const float* adj = (const float*)d_in[1];
    const float* W1  = (const float*)d_in[2];
    const float* b1  = (const float*)d_in[3];
    const float* g1  = (const float*)d_in[4];
    const float* be1 = (const float*)d_in[5];
    const float* W2  = (const float*)d_in[6];
    const float* b2  = (const float*)d_in[7];
    const float* g2  = (const float*)d_in[8];
    const float* be2 = (const float*)d_in[9];
    const float* W3  = (const float*)d_in[10];
    const float* b3  = (const float*)d_in[11];
    const float* Wp1 = (const float*)d_in[12];
    const float* bp1 = (const float*)d_in[13];
    const float* Wp2 = (const float*)d_in[14];
    const float* bp2 = (const float*)d_in[15];
    float* zOut   = (float*)d_out;
    float* embOut = zOut + (size_t)NN * EE;

    char* ws = (char*)d_ws;
    size_t off = 0;
    auto alloc = [&](size_t bytes) -> void* {
        off = (off + 255) & ~(size_t)255;
        void* p = ws + off; off += bytes; return p;
    };

    const size_t adjElems = (size_t)NN * NN;
    bool cacheAdj = ws_size >= adjElems * 2 + 100000000ULL;
    u16* adjb = cacheAdj ? (u16*)alloc(adjElems * 2) : nullptr;

    u16* xW1t   = (u16*)alloc((size_t)DD * NN * 2);
    u16* hW2t   = (u16*)alloc((size_t)DD * NN * 2);
    u16* h2W3t  = (u16*)alloc((size_t)EE * NN * 2);
    u16* hbf    = (u16*)alloc((size_t)NN * DD * 2);
    float* hf32 = (float*)alloc((size_t)NN * DD * 4);
    u16* h2bf   = (u16*)alloc((size_t)NN * DD * 2);
    u16* embbf  = (u16*)alloc((size_t)NN * EE * 2);
    u16* p1bf   = (u16*)alloc((size_t)NN * EE * 2);
    u16* W1t    = (u16*)alloc(65536 * 2);
    u16* W2t    = (u16*)alloc(65536 * 2);
    u16* W3t    = (u16*)alloc(32768 * 2);
    u16* Wp1t   = (u16*)alloc(16384 * 2);
    u16* Wp2t   = (u16*)alloc(16384 * 2);

    const int S = 4;
    float* part = (float*)alloc((size_t)S * NN * DD * 4);
    const int KCH = 3008;   // 94 x BK=32 steps per chunk (12000 = 3*3008 + 2976)

    prep_k<<<768, 256, 0, stream>>>(W1, W2, W3, Wp1, Wp2, W1t, W2t, W3t, Wp1t, Wp2t);

    // S1: xW1t[256][12000] = W1t @ x^T + b1
    gemm_k<64, 3, false, true, false, 1, false, true><<<4 * 188, 256, 0, stream>>>(
        W1t, x, xW1t, nullptr, b1, DD, NN, DD, DD, DD, 4, 188, DD);

    // P1: part[s] = adj @ xW1 (fp32 adj, fused cvt, dump bf16 adj) -- r3 kernel
    if (cacheAdj)
        gemm_k<256, 3, true, false, true, 0, false, false><<<188 * S, 256, 0, stream>>>(
            adj, xW1t, part, adjb, nullptr, NN, DD, NN, NN, NN, 188, 1, KCH);
    else
        gemm_k<256, 3, true, false, false, 0, false, false><<<188 * S, 256, 0, stream>>>(
            adj, xW1t, part, nullptr, nullptr, NN, DD, NN, NN, NN, 188, 1, KCH);

    // E1: h = relu(LN(t1 + x)) -> hbf (bf16) + hf32 (residual)
    ln_k<<<750, 256, 0, stream>>>(part, (long)NN * DD, S, x, g1, be1, hbf, hf32, NN);

    // S2: hW2t = W2t @ h^T + b2
    gemm_k<64, 4, false, false, false, 1, false, true><<<4 * 188, 256, 0, stream>>>(
        W2t, hbf, hW2t, nullptr, b2, DD, NN, DD, DD, DD, 4, 188, DD);

    // P2: part[s] = adj @ hW2 -- counted-vmcnt kernel (NLOADS=5)
    if (cacheAdj)
        padj_k<256, 2, 5><<<188 * S, 256, 0, stream>>>(
            adjb, hW2t, part, NN, NN, NN, NN, 188, KCH);
    else
        gemm_k<256, 3, true, false, false, 0, false, false><<<188 * S, 256, 0, stream>>>(
            adj, hW2t, part, nullptr, nullptr, NN, DD, NN, NN, NN, 188, 1, KCH);

    // E2: h2 = relu(LN(t2 + h))
    ln_k<<<750, 256, 0, stream>>>(part, (long)NN * DD, S, hf32, g2, be2, h2bf, nullptr, NN);

    // S3: h2W3t[128][12000] = W3t @ h2^T + b3
    gemm_k<64, 4, false, false, false, 1, false, true><<<2 * 188, 256, 0, stream>>>(
        W3t, h2bf, h2W3t, nullptr, b3, EE, NN, DD, DD, DD, 2, 188, DD);

    // P3: part[s] = adj @ h2W3 -- counted-vmcnt kernel (NLOADS=3)
    if (cacheAdj)
        padj_k<128, 4, 3><<<188 * S, 256, 0, stream>>>(
            adjb, h2W3t, part, NN, NN, NN, NN, 188, KCH);
    else
        gemm_k<128, 3, true, false, false, 0, false, false><<<188 * S, 256, 0, stream>>>(
            adj, h2W3t, part, nullptr, nullptr, NN, EE, NN, NN, NN, 188, 1, KCH);

    // E3: embedding out (fp32) + bf16 copy for proj head
    sum_k<<<1500, 256, 0, stream>>>(part, (long)NN * EE, S, embOut, embbf, NN * EE / 4);

    // S4: p1 = relu(emb @ Wp1 + bp1)
    gemm_k<128, 4, false, false, false, 2, true, true><<<188, 256, 0, stream>>>(
        embbf, Wp1t, p1bf, nullptr, bp1, NN, EE, EE, EE, EE, 188, 1, EE);

    // S5: z = p1 @ Wp2 + bp2 -> d_out (fp32)
    gemm_k<128, 4, false, false, false, 2, false, false><<<188, 256, 0, stream>>>(
        p1bf, Wp2t, zOut, nullptr, bp2, NN, EE, EE, EE, EE, 188, 1, EE);
}